// Round 2
// baseline (1789.393 us; speedup 1.0000x reference)
//
#include <hip/hip_runtime.h>
#include <cstdint>
#include <cstddef>

#define INDIM 512
#define HIDD  256
#define OUTD  32

// ---- bf16 <-> f32 helpers ----
static inline __device__ float b2f(unsigned short u) {
  union { float f; unsigned int i; } v; v.i = ((unsigned int)u) << 16; return v.f;
}
static inline __device__ unsigned short f2b(float f) {
  union { float f; unsigned int i; } v; v.f = f;
  unsigned int x = v.i;
  x += 0x7fffu + ((x >> 16) & 1u);   // round-to-nearest-even
  return (unsigned short)(x >> 16);
}

// ---- runtime dtype probe ----
// flags[0] = 1 if float tensors are bf16 on device, 0 if f32
// flags[1] = 1 if edge_index is int64 on device, 0 if int32
__global__ __launch_bounds__(256) void probe_kernel(
    const unsigned int* __restrict__ feat, const unsigned int* __restrict__ eidx,
    int* __restrict__ flags)
{
  int t = threadIdx.x;
  __shared__ int cnt, oddnz;
  if (t == 0) { cnt = 0; oddnz = 0; }
  __syncthreads();
  // feature dtype: is the LOW half of each u32 a plausible bf16 value?
  unsigned int w = feat[t];
  unsigned short lo = (unsigned short)(w & 0xFFFFu);
  int e = (lo >> 7) & 0xFF;
  int plausible = ((lo & 0x7FFF) == 0) || (e >= 0x60 && e <= 0x9F);
  atomicAdd(&cnt, plausible);
  // index dtype: int64 values < 2^31 have zero high words at odd u32 positions
  if (t & 1) { if (eidx[t] != 0u) atomicAdd(&oddnz, 1); }
  __syncthreads();
  if (t == 0) { flags[0] = (cnt >= 192) ? 1 : 0; flags[1] = (oddnz == 0) ? 1 : 0; }
}

// ---- normalize edge_index to int32 src/dst arrays ----
__global__ __launch_bounds__(256) void convert_idx(
    const unsigned int* __restrict__ eidx, int* __restrict__ srcN, int* __restrict__ dstN,
    int E, const int* __restrict__ flags)
{
  int ee = blockIdx.x * 256 + threadIdx.x;
  if (ee >= E) return;
  if (flags[1]) {
    srcN[ee] = (int)eidx[2 * (size_t)ee];
    dstN[ee] = (int)eidx[2 * ((size_t)E + ee)];
  } else {
    srcN[ee] = (int)eidx[ee];
    dstN[ee] = (int)eidx[(size_t)E + ee];
  }
}

static inline __device__ float ldadapt(const void* p, size_t i, int isbf) {
  return isbf ? b2f(((const unsigned short*)p)[i]) : ((const float*)p)[i];
}

// ---- weight prep: (bf16|f32) -> f32, plus transposes ----
__global__ __launch_bounds__(256) void prep_weights(
    const void* __restrict__ W1, const void* __restrict__ W2,
    const void* __restrict__ aS, const void* __restrict__ aD,
    float* __restrict__ W1f, float* __restrict__ W1t,
    float* __restrict__ W2f, float* __restrict__ W2t,
    float* __restrict__ atS, float* __restrict__ atD,
    const int* __restrict__ flags)
{
  const int fb = flags[0];
  int i = blockIdx.x * 256 + threadIdx.x;
  if (i < INDIM * HIDD) {               // W1: [512][256]
    int r = i >> 8, c = i & 255;
    float w0 = ldadapt(W1, i, fb);
    W1f[i] = w0;
    W1t[c * INDIM + r] = w0;            // W1t[k][n] = W1[n][k]
  }
  if (i < HIDD * OUTD) {                // W2: [256][32]
    int r = i >> 5, c = i & 31;
    float w0 = ldadapt(W2, i, fb);
    W2f[i] = w0;
    W2t[c * HIDD + r] = w0;             // W2t[k][n] = W2[n][k]
  }
  if (i < HIDD) { atS[i] = ldadapt(aS, i, fb); atD[i] = ldadapt(aD, i, fb); }
}

// ---- tiled GEMM: C[M,Nn] = A[M,K] @ B[K,Nn] ----
// AM: 0 = A f32, 1 = A bf16, 2 = A adaptive (flag)
// SM: 0 = store f32 Cf, 1 = store bf16 Cb, 2 = store adaptive to Out+outOff
template<int AM, int SM>
__global__ __launch_bounds__(256) void gemm_tile(
    const void* __restrict__ Av, const float* __restrict__ B,
    float* __restrict__ Cf, unsigned short* __restrict__ Cb,
    void* __restrict__ Out, size_t outOff,
    const int* __restrict__ flags, int M, int K, int Nn)
{
  const int fb = flags[0];
  __shared__ float As[64][17];
  __shared__ float Bs[16][68];
  int tid = threadIdx.x;
  int tx = tid & 15, ty = tid >> 4;
  int rowBase = blockIdx.y * 64;
  int colBase = blockIdx.x * 64;
  float acc[4][4] = {};

  for (int kt = 0; kt < K; kt += 16) {
    {
      int r = tid >> 2, kk = (tid & 3) << 2;
      int gr = rowBase + r;
      float4 av = make_float4(0.f, 0.f, 0.f, 0.f);
      if (gr < M) {
        size_t off = (size_t)gr * K + kt + kk;
        if (AM == 0) {
          av = *(const float4*)((const float*)Av + off);
        } else if (AM == 1) {
          ushort4 u = *(const ushort4*)((const unsigned short*)Av + off);
          av = make_float4(b2f(u.x), b2f(u.y), b2f(u.z), b2f(u.w));
        } else {
          if (fb) {
            ushort4 u = *(const ushort4*)((const unsigned short*)Av + off);
            av = make_float4(b2f(u.x), b2f(u.y), b2f(u.z), b2f(u.w));
          } else {
            av = *(const float4*)((const float*)Av + off);
          }
        }
      }
      As[r][kk] = av.x; As[r][kk + 1] = av.y; As[r][kk + 2] = av.z; As[r][kk + 3] = av.w;
    }
    {
      int kk = tid >> 4, c = (tid & 15) << 2;
      float4 bv = *(const float4*)(B + (size_t)(kt + kk) * Nn + colBase + c);
      *(float4*)&Bs[kk][c] = bv;
    }
    __syncthreads();
#pragma unroll
    for (int kk = 0; kk < 16; ++kk) {
      float a0 = As[ty * 4 + 0][kk], a1 = As[ty * 4 + 1][kk];
      float a2 = As[ty * 4 + 2][kk], a3 = As[ty * 4 + 3][kk];
      float b0 = Bs[kk][tx * 4 + 0], b1 = Bs[kk][tx * 4 + 1];
      float b2 = Bs[kk][tx * 4 + 2], b3 = Bs[kk][tx * 4 + 3];
      acc[0][0] += a0 * b0; acc[0][1] += a0 * b1; acc[0][2] += a0 * b2; acc[0][3] += a0 * b3;
      acc[1][0] += a1 * b0; acc[1][1] += a1 * b1; acc[1][2] += a1 * b2; acc[1][3] += a1 * b3;
      acc[2][0] += a2 * b0; acc[2][1] += a2 * b1; acc[2][2] += a2 * b2; acc[2][3] += a2 * b3;
      acc[3][0] += a3 * b0; acc[3][1] += a3 * b1; acc[3][2] += a3 * b2; acc[3][3] += a3 * b3;
    }
    __syncthreads();
  }
#pragma unroll
  for (int i = 0; i < 4; ++i) {
    int r = rowBase + ty * 4 + i;
    if (r >= M) continue;
#pragma unroll
    for (int j = 0; j < 4; ++j) {
      int c = colBase + tx * 4 + j;
      size_t idx = (size_t)r * Nn + c;
      if (SM == 0) Cf[idx] = acc[i][j];
      else if (SM == 1) Cb[idx] = f2b(acc[i][j]);
      else {
        if (fb) ((unsigned short*)Out)[outOff + idx] = f2b(acc[i][j]);
        else    ((float*)Out)[outOff + idx] = acc[i][j];
      }
    }
  }
}

// ---- a_src / a_dst: one wave per node, dot(xp1_row, att); P is bf16 ----
__global__ __launch_bounds__(256) void rowdots(
    const unsigned short* __restrict__ P, const float* __restrict__ atS,
    const float* __restrict__ atD,
    float* __restrict__ asrc, float* __restrict__ adst, int N)
{
  int wave = threadIdx.x >> 6, lane = threadIdx.x & 63;
  int node = blockIdx.x * 4 + wave;
  if (node >= N) return;
  ushort4 u = *(const ushort4*)(P + (size_t)node * HIDD + lane * 4);
  float4 v = make_float4(b2f(u.x), b2f(u.y), b2f(u.z), b2f(u.w));
  float4 s = *(const float4*)(atS + lane * 4);
  float4 d = *(const float4*)(atD + lane * 4);
  float s1 = v.x * s.x + v.y * s.y + v.z * s.z + v.w * s.w;
  float s2 = v.x * d.x + v.y * d.y + v.z * d.z + v.w * d.w;
#pragma unroll
  for (int off = 32; off; off >>= 1) {
    s1 += __shfl_down(s1, off);
    s2 += __shfl_down(s2, off);
  }
  if (lane == 0) { asrc[node] = s1; adst[node] = s2; }
}

// ---- CSR build ----
__global__ __launch_bounds__(256) void deg_kernel(const int* __restrict__ dst, int* __restrict__ deg, int E) {
  int e = blockIdx.x * 256 + threadIdx.x;
  if (e < E) atomicAdd(&deg[dst[e]], 1);
}

__global__ __launch_bounds__(1024) void scan_kernel(const int* __restrict__ deg, int* __restrict__ offs, int N) {
  __shared__ int part[1024];
  int t = threadIdx.x;
  int chunk = (N + 1023) >> 10;
  int beg = t * chunk;
  int end = beg + chunk; if (end > N) end = N;
  int s = 0;
  for (int i = beg; i < end; ++i) s += deg[i];
  part[t] = s;
  __syncthreads();
  for (int off = 1; off < 1024; off <<= 1) {
    int v = (t >= off) ? part[t - off] : 0;
    __syncthreads();
    part[t] += v;
    __syncthreads();
  }
  int run = (t == 0) ? 0 : part[t - 1];
  for (int i = beg; i < end; ++i) { offs[i] = run; run += deg[i]; }
  if (t == 1023) offs[N] = part[1023];
}

__global__ __launch_bounds__(256) void fill_kernel(const int* __restrict__ dst, int* __restrict__ cur,
                                                   int* __restrict__ perm, int E) {
  int e = blockIdx.x * 256 + threadIdx.x;
  if (e < E) {
    int pos = atomicAdd(&cur[dst[e]], 1);
    perm[pos] = e;
  }
}

// ---- edge coefficient: t = exp(sigmoid(asrc[s]+adst[d])); srec[d] += t ----
__global__ __launch_bounds__(256) void coef_kernel(
    const int* __restrict__ src, const int* __restrict__ dst,
    const float* __restrict__ asrc, const float* __restrict__ adst,
    float* __restrict__ coef, float* __restrict__ srec, int E)
{
  int e = blockIdx.x * 256 + threadIdx.x;
  if (e >= E) return;
  float x = asrc[src[e]] + adst[dst[e]];
  float al = 1.f / (1.f + __expf(-x));    // sigmoid in (0,1): segment-max unneeded
  float t = __expf(al);
  coef[e] = t;
  atomicAdd(&srec[dst[e]], t);
}

__global__ __launch_bounds__(256) void norm_kernel(
    const int* __restrict__ dst, const float* __restrict__ srec, float* __restrict__ coef, int E)
{
  int e = blockIdx.x * 256 + threadIdx.x;
  if (e >= E) return;
  coef[e] = coef[e] / (srec[dst[e]] + 1e-16f);
}

// ---- per-node aggregation + ELU; xp and hout are bf16 ----
__global__ __launch_bounds__(256) void agg_elu(
    const unsigned short* __restrict__ xp, const float* __restrict__ coef,
    const int* __restrict__ src, const int* __restrict__ perm,
    const int* __restrict__ offs, unsigned short* __restrict__ hout)
{
  int node = blockIdx.x;
  int c = threadIdx.x;
  __shared__ int   ssv[256];
  __shared__ float sw[256];
  int s0 = offs[node], s1 = offs[node + 1];
  float acc = 0.f;
  for (int base = s0; base < s1; base += 256) {
    int cnt = s1 - base; if (cnt > 256) cnt = 256;
    if (c < cnt) {
      int e = perm[base + c];
      ssv[c] = src[e];
      sw[c] = coef[e];
    }
    __syncthreads();
#pragma unroll 4
    for (int j = 0; j < cnt; ++j)
      acc += sw[j] * b2f(xp[(size_t)ssv[j] * HIDD + c]);
    __syncthreads();
  }
  float r = acc > 0.f ? acc : expm1f(acc);
  hout[(size_t)node * HIDD + c] = f2b(r);
}

// ---- h2 = h1 @ W2 ([N,256]x[256,32]) -> f32 C2 + adaptive out ----
__global__ __launch_bounds__(256) void gemm_h2(
    const unsigned short* __restrict__ H1, const float* __restrict__ W2f,
    float* __restrict__ C2, void* __restrict__ Out,
    const int* __restrict__ flags, int M)
{
  const int fb = flags[0];
  __shared__ float Bs[HIDD][33];
  __shared__ float As[8][HIDD];
  int tid = threadIdx.x;
  int tx = tid & 31, ty = tid >> 5;
  int row0 = blockIdx.x * 8;
#pragma unroll
  for (int j = 0; j < 32; ++j) {
    int idx = tid + 256 * j;
    Bs[idx >> 5][idx & 31] = W2f[idx];
  }
#pragma unroll
  for (int j = 0; j < 8; ++j) {
    int idx = tid + 256 * j;
    int r = idx >> 8, k = idx & 255;
    As[r][k] = (row0 + r < M) ? b2f(H1[(size_t)(row0 + r) * HIDD + k]) : 0.f;
  }
  __syncthreads();
  float acc = 0.f;
#pragma unroll 8
  for (int k = 0; k < HIDD; ++k) acc += As[ty][k] * Bs[k][tx];
  int row = row0 + ty;
  if (row < M) {
    size_t idx = (size_t)row * OUTD + tx;
    C2[idx] = acc;
    if (fb) ((unsigned short*)Out)[idx] = f2b(acc);
    else    ((float*)Out)[idx] = acc;
  }
}

extern "C" void kernel_launch(void* const* d_in, const int* in_sizes, int n_in,
                              void* d_out, int out_size, void* d_ws, size_t ws_size,
                              hipStream_t stream)
{
  const void*         feat = d_in[0];
  const unsigned int* eidx = (const unsigned int*)d_in[1];
  const void*         W1   = d_in[2];
  const void*         W2   = d_in[3];
  const void*         aS   = d_in[4];
  const void*         aD   = d_in[5];

  const int N = in_sizes[0] / INDIM;
  const int E = in_sizes[1] / 2;

  // ---- workspace carve-up (~145 MB) ----
  char* w = (char*)d_ws;
  auto alloc = [&](size_t bytes) -> char* {
    char* p = w; w += (bytes + 255) & ~(size_t)255; return p;
  };
  unsigned short* P  = (unsigned short*)alloc((size_t)N * HIDD * 2);  // xp1 / xp3 (bf16)
  unsigned short* H  = (unsigned short*)alloc((size_t)N * HIDD * 2);  // h1 / h3 (bf16)
  float* C2   = (float*)alloc((size_t)N * OUTD * 4);                  // h2 f32
  float* asrc = (float*)alloc((size_t)N * 4);
  float* adst = (float*)alloc((size_t)N * 4);
  float* srec = (float*)alloc((size_t)N * 4);
  float* coef = (float*)alloc((size_t)E * 4);
  int*   deg  = (int*)alloc((size_t)N * 4);
  int*   offs = (int*)alloc((size_t)(N + 1) * 4);
  int*   cur  = (int*)alloc((size_t)N * 4);
  int*   perm = (int*)alloc((size_t)E * 4);
  int*   srcN = (int*)alloc((size_t)E * 4);
  int*   dstN = (int*)alloc((size_t)E * 4);
  float* W1f  = (float*)alloc((size_t)INDIM * HIDD * 4);
  float* W1t  = (float*)alloc((size_t)INDIM * HIDD * 4);
  float* W2f  = (float*)alloc((size_t)HIDD * OUTD * 4);
  float* W2t  = (float*)alloc((size_t)HIDD * OUTD * 4);
  float* atS  = (float*)alloc((size_t)HIDD * 4);
  float* atD  = (float*)alloc((size_t)HIDD * 4);
  int*   flags = (int*)alloc(64);

  hipMemsetAsync(deg, 0, (size_t)N * 4, stream);
  hipMemsetAsync(srec, 0, (size_t)N * 4, stream);

  probe_kernel<<<1, 256, 0, stream>>>((const unsigned int*)feat, eidx, flags);

  const int eb = (E + 255) / 256;
  convert_idx<<<eb, 256, 0, stream>>>(eidx, srcN, dstN, E, flags);
  prep_weights<<<512, 256, 0, stream>>>(W1, W2, aS, aD, W1f, W1t, W2f, W2t, atS, atD, flags);

  // xp1 = features @ W1
  {
    dim3 g(HIDD / 64, (N + 63) / 64);
    gemm_tile<2, 1><<<g, 256, 0, stream>>>(feat, W1f, nullptr, P, nullptr, 0, flags, N, INDIM, HIDD);
  }

  rowdots<<<(N + 3) / 4, 256, 0, stream>>>(P, atS, atD, asrc, adst, N);

  deg_kernel<<<eb, 256, 0, stream>>>(dstN, deg, E);
  scan_kernel<<<1, 1024, 0, stream>>>(deg, offs, N);
  hipMemcpyAsync(cur, offs, (size_t)N * 4, hipMemcpyDeviceToDevice, stream);
  fill_kernel<<<eb, 256, 0, stream>>>(dstN, cur, perm, E);
  coef_kernel<<<eb, 256, 0, stream>>>(srcN, dstN, asrc, adst, coef, srec, E);
  norm_kernel<<<eb, 256, 0, stream>>>(dstN, srec, coef, E);

  // GAT layer 1: h1 = elu(agg(xp1))
  agg_elu<<<N, 256, 0, stream>>>(P, coef, srcN, perm, offs, H);

  // h2 = h1 @ W2 -> output 0 (adaptive dtype) + f32 copy
  gemm_h2<<<(N + 7) / 8, 256, 0, stream>>>(H, W2f, C2, d_out, flags, N);

  // xp3 = h2 @ W2^T
  {
    dim3 g(HIDD / 64, (N + 63) / 64);
    gemm_tile<0, 1><<<g, 256, 0, stream>>>(C2, W2t, nullptr, P, nullptr, 0, flags, N, OUTD, HIDD);
  }

  // GAT layer 2 (identical coefficients): h3 = elu(agg(xp3))
  agg_elu<<<N, 256, 0, stream>>>(P, coef, srcN, perm, offs, H);

  // h4 = h3 @ W1^T -> output 1 (adaptive dtype)
  {
    dim3 g(INDIM / 64, (N + 63) / 64);
    gemm_tile<1, 2><<<g, 256, 0, stream>>>(H, W1t, nullptr, nullptr, d_out, (size_t)N * OUTD, flags, N, HIDD, INDIM);
  }
}

// Round 3
// 1468.331 us; speedup vs baseline: 1.2187x; 1.2187x over previous
//
#include <hip/hip_runtime.h>
#include <cstdint>
#include <cstddef>

#define INDIM 512
#define HIDD  256
#define OUTD  32

typedef __attribute__((ext_vector_type(4))) float f32x4;
typedef __attribute__((ext_vector_type(8))) short bf16x8;

// ---- bf16 <-> f32 helpers ----
static inline __device__ float b2f(unsigned short u) {
  union { float f; unsigned int i; } v; v.i = ((unsigned int)u) << 16; return v.f;
}
static inline __device__ unsigned short f2b(float f) {
  union { float f; unsigned int i; } v; v.f = f;
  unsigned int x = v.i;
  x += 0x7fffu + ((x >> 16) & 1u);   // round-to-nearest-even
  return (unsigned short)(x >> 16);
}

// ---- runtime dtype probe ----
// flags[0] = 1 if float tensors are bf16 on device, 0 if f32
// flags[1] = 1 if edge_index is int64 on device, 0 if int32
__global__ __launch_bounds__(256) void probe_kernel(
    const unsigned int* __restrict__ feat, const unsigned int* __restrict__ eidx,
    int* __restrict__ flags)
{
  int t = threadIdx.x;
  __shared__ int cnt, oddnz;
  if (t == 0) { cnt = 0; oddnz = 0; }
  __syncthreads();
  unsigned int w = feat[t];
  unsigned short lo = (unsigned short)(w & 0xFFFFu);
  int e = (lo >> 7) & 0xFF;
  int plausible = ((lo & 0x7FFF) == 0) || (e >= 0x60 && e <= 0x9F);
  atomicAdd(&cnt, plausible);
  if (t & 1) { if (eidx[t] != 0u) atomicAdd(&oddnz, 1); }
  __syncthreads();
  if (t == 0) { flags[0] = (cnt >= 192) ? 1 : 0; flags[1] = (oddnz == 0) ? 1 : 0; }
}

// ---- normalize edge_index to int32 src/dst ----
__global__ __launch_bounds__(256) void convert_idx(
    const unsigned int* __restrict__ eidx, int* __restrict__ srcN, int* __restrict__ dstN,
    int E, const int* __restrict__ flags)
{
  int ee = blockIdx.x * 256 + threadIdx.x;
  if (ee >= E) return;
  if (flags[1]) {
    srcN[ee] = (int)eidx[2 * (size_t)ee];
    dstN[ee] = (int)eidx[2 * ((size_t)E + ee)];
  } else {
    srcN[ee] = (int)eidx[ee];
    dstN[ee] = (int)eidx[(size_t)E + ee];
  }
}

static inline __device__ float ldadapt(const void* p, size_t i, int isbf) {
  return isbf ? b2f(((const unsigned short*)p)[i]) : ((const float*)p)[i];
}

// ---- weight prep: W1b [512][256] bf16, W1tb [256][512] bf16, W2f f32, att f32 ----
__global__ __launch_bounds__(256) void prep_weights(
    const void* __restrict__ W1, const void* __restrict__ W2,
    const void* __restrict__ aS, const void* __restrict__ aD,
    unsigned short* __restrict__ W1b, unsigned short* __restrict__ W1tb,
    float* __restrict__ W2f,
    float* __restrict__ atS, float* __restrict__ atD,
    const int* __restrict__ flags)
{
  const int fb = flags[0];
  int i = blockIdx.x * 256 + threadIdx.x;
  if (i < INDIM * HIDD) {               // W1: [512][256]
    int r = i >> 8, c = i & 255;
    float w0 = ldadapt(W1, i, fb);
    unsigned short wb = f2b(w0);
    W1b[i] = wb;                        // [k=512][n=256] row-major == Bt for h4 (n,k)=(INDIM,HIDD)? no: used as Bt[n=512 rows][k=256]
    W1tb[c * INDIM + r] = wb;           // [256][512]: Bt for xp1 (n=HIDD rows, k=INDIM)
  }
  if (i < HIDD * OUTD) W2f[i] = ldadapt(W2, i, fb);
  if (i < HIDD) { atS[i] = ldadapt(aS, i, fb); atD[i] = ldadapt(aD, i, fb); }
}

// ---- M2 = W2 @ W2^T : [256][256] bf16 (symmetric) ----
__global__ __launch_bounds__(256) void m2_kernel(const float* __restrict__ W2f,
                                                 unsigned short* __restrict__ M2b)
{
  int i = blockIdx.x, j = threadIdx.x;
  float s = 0.f;
#pragma unroll
  for (int o = 0; o < OUTD; ++o) s += W2f[i * OUTD + o] * W2f[j * OUTD + o];
  M2b[i * HIDD + j] = f2b(s);
}

// =====================================================================
// MFMA NT GEMM: C[M][Nn] = A[M][K] @ Bt[Nn][K]^T
// BM x BN block tile, BK=64, 256 threads = 4 waves, each wave 64x64 out.
// LDS: A and Bt tiles stored [rows][64] bf16 with 16B-granule XOR swizzle.
// AMODE: 0 = A bf16; 1 = A adaptive (f32 converted in-flight unless flags[0])
// OUTMODE: 0 = store bf16 to Cb; 1 = adaptive store to Out+outOff (flag dtype)
// =====================================================================
template<int BM, int BN, int AMODE, int OUTMODE>
__global__ __launch_bounds__(256) void gemm_nt(
    const void* __restrict__ Av, const unsigned short* __restrict__ Bt,
    unsigned short* __restrict__ Cb, void* __restrict__ Out, size_t outOff,
    const int* __restrict__ flags, int M, int Nn, int K)
{
  constexpr int BK = 64;
  constexpr int WC = BN / 64;          // waves along N
  constexpr int AG = BM * 8 / 256;     // 16B A-granules per thread
  constexpr int BG = BN * 8 / 256;
  __shared__ unsigned short Als[BM * BK];
  __shared__ unsigned short Bls[BN * BK];

  const int tid = threadIdx.x;
  const int lane = tid & 63, wid = tid >> 6;
  const int wr = wid / WC, wc = wid % WC;
  const int rowBase = blockIdx.y * BM, colBase = blockIdx.x * BN;
  const int fb = flags[0];

  f32x4 acc[4][4] = {};
  int4 ra[AG], rb[BG];

  auto loadT = [&](int kt) {
#pragma unroll
    for (int i = 0; i < AG; ++i) {
      int G = tid + 256 * i, row = G >> 3, g = G & 7;
      int gr = rowBase + row; if (gr > M - 1) gr = M - 1;   // clamp: no OOB, stores are guarded
      size_t off = (size_t)gr * K + kt + g * 8;
      if (AMODE == 1 && !fb) {
        const float* Af = (const float*)Av;
        float4 lo = *(const float4*)(Af + off);
        float4 hi = *(const float4*)(Af + off + 4);
        union { unsigned short us[8]; int4 v; } cv;
        cv.us[0] = f2b(lo.x); cv.us[1] = f2b(lo.y); cv.us[2] = f2b(lo.z); cv.us[3] = f2b(lo.w);
        cv.us[4] = f2b(hi.x); cv.us[5] = f2b(hi.y); cv.us[6] = f2b(hi.z); cv.us[7] = f2b(hi.w);
        ra[i] = cv.v;
      } else {
        ra[i] = *(const int4*)((const unsigned short*)Av + off);
      }
    }
#pragma unroll
    for (int i = 0; i < BG; ++i) {
      int G = tid + 256 * i, row = G >> 3, g = G & 7;
      rb[i] = *(const int4*)(Bt + (size_t)(colBase + row) * K + kt + g * 8);
    }
  };

  auto writeLDS = [&]() {
#pragma unroll
    for (int i = 0; i < AG; ++i) {
      int G = tid + 256 * i, row = G >> 3, g = (G & 7) ^ (row & 7);
      *(int4*)(Als + row * BK + g * 8) = ra[i];
    }
#pragma unroll
    for (int i = 0; i < BG; ++i) {
      int G = tid + 256 * i, row = G >> 3, g = (G & 7) ^ (row & 7);
      *(int4*)(Bls + row * BK + g * 8) = rb[i];
    }
  };

  auto compute = [&]() {
    bf16x8 af[4], bfr[4];
#pragma unroll
    for (int ks = 0; ks < 2; ++ks) {
#pragma unroll
      for (int mi = 0; mi < 4; ++mi) {
        int row = wr * 64 + mi * 16 + (lane & 15);
        int g = (ks * 4 + (lane >> 4)) ^ (row & 7);
        af[mi] = *(const bf16x8*)(Als + row * BK + g * 8);
      }
#pragma unroll
      for (int ni = 0; ni < 4; ++ni) {
        int row = wc * 64 + ni * 16 + (lane & 15);
        int g = (ks * 4 + (lane >> 4)) ^ (row & 7);
        bfr[ni] = *(const bf16x8*)(Bls + row * BK + g * 8);
      }
#pragma unroll
      for (int mi = 0; mi < 4; ++mi)
#pragma unroll
        for (int ni = 0; ni < 4; ++ni)
          acc[mi][ni] = __builtin_amdgcn_mfma_f32_16x16x32_bf16(af[mi], bfr[ni], acc[mi][ni], 0, 0, 0);
    }
  };

  const int nt = K / BK;
  loadT(0);
  for (int t = 0; t < nt; ++t) {
    writeLDS();
    __syncthreads();
    if (t + 1 < nt) loadT((t + 1) * BK);   // prefetch overlaps MFMA below
    compute();
    __syncthreads();
  }

  // C/D fragment: col = lane&15, row = (lane>>4)*4 + reg   [measured m89/m91]
#pragma unroll
  for (int mi = 0; mi < 4; ++mi) {
    int r0 = rowBase + wr * 64 + mi * 16 + (lane >> 4) * 4;
#pragma unroll
    for (int ni = 0; ni < 4; ++ni) {
      int c = colBase + wc * 64 + ni * 16 + (lane & 15);
#pragma unroll
      for (int v = 0; v < 4; ++v) {
        int r = r0 + v;
        if (r < M) {
          size_t idx = (size_t)r * Nn + c;
          if (OUTMODE == 0) Cb[idx] = f2b(acc[mi][ni][v]);
          else {
            if (fb) ((unsigned short*)Out)[outOff + idx] = f2b(acc[mi][ni][v]);
            else    ((float*)Out)[outOff + idx] = acc[mi][ni][v];
          }
        }
      }
    }
  }
}

// ---- a_src / a_dst: one wave per node, dot(xp1_row, att); P is bf16 ----
__global__ __launch_bounds__(256) void rowdots(
    const unsigned short* __restrict__ P, const float* __restrict__ atS,
    const float* __restrict__ atD,
    float* __restrict__ asrc, float* __restrict__ adst, int N)
{
  int wave = threadIdx.x >> 6, lane = threadIdx.x & 63;
  int node = blockIdx.x * 4 + wave;
  if (node >= N) return;
  ushort4 u = *(const ushort4*)(P + (size_t)node * HIDD + lane * 4);
  float4 v = make_float4(b2f(u.x), b2f(u.y), b2f(u.z), b2f(u.w));
  float4 s = *(const float4*)(atS + lane * 4);
  float4 d = *(const float4*)(atD + lane * 4);
  float s1 = v.x * s.x + v.y * s.y + v.z * s.z + v.w * s.w;
  float s2 = v.x * d.x + v.y * d.y + v.z * d.z + v.w * d.w;
#pragma unroll
  for (int off = 32; off; off >>= 1) {
    s1 += __shfl_down(s1, off);
    s2 += __shfl_down(s2, off);
  }
  if (lane == 0) { asrc[node] = s1; adst[node] = s2; }
}

// ---- CSR build ----
__global__ __launch_bounds__(256) void deg_kernel(const int* __restrict__ dst, int* __restrict__ deg, int E) {
  int e = blockIdx.x * 256 + threadIdx.x;
  if (e < E) atomicAdd(&deg[dst[e]], 1);
}

__global__ __launch_bounds__(1024) void scan_kernel(const int* __restrict__ deg, int* __restrict__ offs, int N) {
  __shared__ int part[1024];
  int t = threadIdx.x;
  int chunk = (N + 1023) >> 10;
  int beg = t * chunk;
  int end = beg + chunk; if (end > N) end = N;
  int s = 0;
  for (int i = beg; i < end; ++i) s += deg[i];
  part[t] = s;
  __syncthreads();
  for (int off = 1; off < 1024; off <<= 1) {
    int v = (t >= off) ? part[t - off] : 0;
    __syncthreads();
    part[t] += v;
    __syncthreads();
  }
  int run = (t == 0) ? 0 : part[t - 1];
  for (int i = beg; i < end; ++i) { offs[i] = run; run += deg[i]; }
  if (t == 1023) offs[N] = part[1023];
}

__global__ __launch_bounds__(256) void fill_kernel(const int* __restrict__ dst, int* __restrict__ cur,
                                                   int* __restrict__ perm, int E) {
  int e = blockIdx.x * 256 + threadIdx.x;
  if (e < E) {
    int pos = atomicAdd(&cur[dst[e]], 1);
    perm[pos] = e;
  }
}

// ---- edge coefficient: t = exp(sigmoid(asrc[s]+adst[d])); srec[d] += t ----
__global__ __launch_bounds__(256) void coef_kernel(
    const int* __restrict__ src, const int* __restrict__ dst,
    const float* __restrict__ asrc, const float* __restrict__ adst,
    float* __restrict__ coef, float* __restrict__ srec, int E)
{
  int e = blockIdx.x * 256 + threadIdx.x;
  if (e >= E) return;
  float x = asrc[src[e]] + adst[dst[e]];
  float al = 1.f / (1.f + __expf(-x));    // sigmoid in (0,1): segment-max unneeded
  float t = __expf(al);
  coef[e] = t;
  atomicAdd(&srec[dst[e]], t);
}

__global__ __launch_bounds__(256) void norm_kernel(
    const int* __restrict__ dst, const float* __restrict__ srec, float* __restrict__ coef, int E)
{
  int e = blockIdx.x * 256 + threadIdx.x;
  if (e >= E) return;
  coef[e] = coef[e] / (srec[dst[e]] + 1e-16f);
}

// ---- per-node aggregation + ELU; xp and hout bf16; 4-way ILP ----
__global__ __launch_bounds__(256) void agg_elu(
    const unsigned short* __restrict__ xp, const float* __restrict__ coef,
    const int* __restrict__ src, const int* __restrict__ perm,
    const int* __restrict__ offs, unsigned short* __restrict__ hout)
{
  int node = blockIdx.x;
  int c = threadIdx.x;
  __shared__ int   ssv[256];
  __shared__ float sw[256];
  int s0 = offs[node], s1 = offs[node + 1];
  float a0 = 0.f, a1 = 0.f, a2 = 0.f, a3 = 0.f;
  for (int base = s0; base < s1; base += 256) {
    int cnt = s1 - base; if (cnt > 256) cnt = 256;
    if (c < cnt) {
      int e = perm[base + c];
      ssv[c] = src[e];
      sw[c] = coef[e];
    }
    __syncthreads();
    int j = 0;
    for (; j + 4 <= cnt; j += 4) {
      float x0 = b2f(xp[(size_t)ssv[j    ] * HIDD + c]);
      float x1 = b2f(xp[(size_t)ssv[j + 1] * HIDD + c]);
      float x2 = b2f(xp[(size_t)ssv[j + 2] * HIDD + c]);
      float x3 = b2f(xp[(size_t)ssv[j + 3] * HIDD + c]);
      a0 += sw[j] * x0; a1 += sw[j + 1] * x1; a2 += sw[j + 2] * x2; a3 += sw[j + 3] * x3;
    }
    for (; j < cnt; ++j) a0 += sw[j] * b2f(xp[(size_t)ssv[j] * HIDD + c]);
    __syncthreads();
  }
  float r = (a0 + a1) + (a2 + a3);
  r = r > 0.f ? r : expm1f(r);
  hout[(size_t)node * HIDD + c] = f2b(r);
}

// ---- h2 = h1 @ W2 ([N,256]x[256,32]) -> adaptive out ----
__global__ __launch_bounds__(256) void gemm_h2(
    const unsigned short* __restrict__ H1, const float* __restrict__ W2f,
    void* __restrict__ Out, const int* __restrict__ flags, int M)
{
  const int fb = flags[0];
  __shared__ float Bs[HIDD][33];
  __shared__ float As[8][HIDD];
  int tid = threadIdx.x;
  int tx = tid & 31, ty = tid >> 5;
  int row0 = blockIdx.x * 8;
#pragma unroll
  for (int j = 0; j < 32; ++j) {
    int idx = tid + 256 * j;
    Bs[idx >> 5][idx & 31] = W2f[idx];
  }
#pragma unroll
  for (int j = 0; j < 8; ++j) {
    int idx = tid + 256 * j;
    int r = idx >> 8, k = idx & 255;
    As[r][k] = (row0 + r < M) ? b2f(H1[(size_t)(row0 + r) * HIDD + k]) : 0.f;
  }
  __syncthreads();
  float acc = 0.f;
#pragma unroll 8
  for (int k = 0; k < HIDD; ++k) acc += As[ty][k] * Bs[k][tx];
  int row = row0 + ty;
  if (row < M) {
    size_t idx = (size_t)row * OUTD + tx;
    if (fb) ((unsigned short*)Out)[idx] = f2b(acc);
    else    ((float*)Out)[idx] = acc;
  }
}

extern "C" void kernel_launch(void* const* d_in, const int* in_sizes, int n_in,
                              void* d_out, int out_size, void* d_ws, size_t ws_size,
                              hipStream_t stream)
{
  const void*         feat = d_in[0];
  const unsigned int* eidx = (const unsigned int*)d_in[1];
  const void*         W1   = d_in[2];
  const void*         W2   = d_in[3];
  const void*         aS   = d_in[4];
  const void*         aD   = d_in[5];

  const int N = in_sizes[0] / INDIM;
  const int E = in_sizes[1] / 2;
  const int M_pad = ((N + 127) / 128) * 128;

  char* w = (char*)d_ws;
  auto alloc = [&](size_t bytes) -> char* {
    char* p = w; w += (bytes + 255) & ~(size_t)255; return p;
  };
  unsigned short* P  = (unsigned short*)alloc((size_t)M_pad * HIDD * 2);  // xp1 / xp3
  unsigned short* H  = (unsigned short*)alloc((size_t)M_pad * HIDD * 2);  // h1 / h3
  float* asrc = (float*)alloc((size_t)N * 4);
  float* adst = (float*)alloc((size_t)N * 4);
  float* srec = (float*)alloc((size_t)N * 4);
  float* coef = (float*)alloc((size_t)E * 4);
  int*   deg  = (int*)alloc((size_t)N * 4);
  int*   offs = (int*)alloc((size_t)(N + 1) * 4);
  int*   cur  = (int*)alloc((size_t)N * 4);
  int*   perm = (int*)alloc((size_t)E * 4);
  int*   srcN = (int*)alloc((size_t)E * 4);
  int*   dstN = (int*)alloc((size_t)E * 4);
  unsigned short* W1b  = (unsigned short*)alloc((size_t)INDIM * HIDD * 2); // [512][256]
  unsigned short* W1tb = (unsigned short*)alloc((size_t)INDIM * HIDD * 2); // [256][512]
  unsigned short* M2b  = (unsigned short*)alloc((size_t)HIDD * HIDD * 2);  // [256][256]
  float* W2f  = (float*)alloc((size_t)HIDD * OUTD * 4);
  float* atS  = (float*)alloc((size_t)HIDD * 4);
  float* atD  = (float*)alloc((size_t)HIDD * 4);
  int*   flags = (int*)alloc(64);

  hipMemsetAsync(deg, 0, (size_t)N * 4, stream);
  hipMemsetAsync(srec, 0, (size_t)N * 4, stream);

  probe_kernel<<<1, 256, 0, stream>>>((const unsigned int*)feat, eidx, flags);

  const int eb = (E + 255) / 256;
  convert_idx<<<eb, 256, 0, stream>>>(eidx, srcN, dstN, E, flags);
  prep_weights<<<512, 256, 0, stream>>>(W1, W2, aS, aD, W1b, W1tb, W2f, atS, atD, flags);
  m2_kernel<<<HIDD, HIDD, 0, stream>>>(W2f, M2b);

  const int mb64 = (N + 63) / 64;

  // xp1 = features @ W1 : A adaptive [N,512], Bt = W1tb [256][512] -> P bf16
  gemm_nt<64, 256, 1, 0><<<dim3(1, mb64), 256, 0, stream>>>(
      feat, W1tb, P, nullptr, 0, flags, N, HIDD, INDIM);

  rowdots<<<(N + 3) / 4, 256, 0, stream>>>(P, atS, atD, asrc, adst, N);

  deg_kernel<<<eb, 256, 0, stream>>>(dstN, deg, E);
  scan_kernel<<<1, 1024, 0, stream>>>(deg, offs, N);
  hipMemcpyAsync(cur, offs, (size_t)N * 4, hipMemcpyDeviceToDevice, stream);
  fill_kernel<<<eb, 256, 0, stream>>>(dstN, cur, perm, E);
  coef_kernel<<<eb, 256, 0, stream>>>(srcN, dstN, asrc, adst, coef, srec, E);
  norm_kernel<<<eb, 256, 0, stream>>>(dstN, srec, coef, E);

  // GAT layer 1: h1 = elu(agg(xp1))
  agg_elu<<<N, 256, 0, stream>>>(P, coef, srcN, perm, offs, H);

  // h2 = h1 @ W2 -> output 0
  gemm_h2<<<(N + 7) / 8, 256, 0, stream>>>(H, W2f, d_out, flags, N);

  // xp3 = h1 @ (W2 W2^T) : A = H bf16, Bt = M2b [256][256] -> P bf16
  gemm_nt<64, 256, 0, 0><<<dim3(1, mb64), 256, 0, stream>>>(
      H, M2b, P, nullptr, 0, flags, N, HIDD, HIDD);

  // GAT layer 2 (identical coefficients): h3 = elu(agg(xp3))
  agg_elu<<<N, 256, 0, stream>>>(P, coef, srcN, perm, offs, H);

  // h4 = h3 @ W1^T : A = H bf16, Bt = W1b [512][256] -> output 1 (adaptive)
  gemm_nt<64, 256, 0, 1><<<dim3(2, mb64), 256, 0, stream>>>(
      H, W1b, nullptr, d_out, (size_t)N * OUTD, flags, N, INDIM, HIDD);
}

// Round 4
// 1184.144 us; speedup vs baseline: 1.5111x; 1.2400x over previous
//
#include <hip/hip_runtime.h>
#include <cstdint>
#include <cstddef>

#define INDIM 512
#define HIDD  256
#define OUTD  32

typedef __attribute__((ext_vector_type(4))) float f32x4;
typedef __attribute__((ext_vector_type(8))) short bf16x8;

// ---- bf16 <-> f32 helpers ----
static inline __device__ float b2f(unsigned short u) {
  union { float f; unsigned int i; } v; v.i = ((unsigned int)u) << 16; return v.f;
}
static inline __device__ unsigned short f2b(float f) {
  union { float f; unsigned int i; } v; v.f = f;
  unsigned int x = v.i;
  x += 0x7fffu + ((x >> 16) & 1u);   // round-to-nearest-even
  return (unsigned short)(x >> 16);
}

// async global->LDS, 16B per lane. LDS dest = wave-uniform base + lane*16.
static __device__ __forceinline__ void gld16(const unsigned short* g, unsigned short* l) {
  __builtin_amdgcn_global_load_lds(
      (const __attribute__((address_space(1))) void*)g,
      (__attribute__((address_space(3))) void*)l, 16, 0, 0);
}

// ---- runtime dtype probe ----
// flags[0] = 1 if float tensors are bf16 on device, 0 if f32
// flags[1] = 1 if edge_index is int64 on device, 0 if int32
__global__ __launch_bounds__(256) void probe_kernel(
    const unsigned int* __restrict__ feat, const unsigned int* __restrict__ eidx,
    int* __restrict__ flags)
{
  int t = threadIdx.x;
  __shared__ int cnt, oddnz;
  if (t == 0) { cnt = 0; oddnz = 0; }
  __syncthreads();
  unsigned int w = feat[t];
  unsigned short lo = (unsigned short)(w & 0xFFFFu);
  int e = (lo >> 7) & 0xFF;
  int plausible = ((lo & 0x7FFF) == 0) || (e >= 0x60 && e <= 0x9F);
  atomicAdd(&cnt, plausible);
  if (t & 1) { if (eidx[t] != 0u) atomicAdd(&oddnz, 1); }
  __syncthreads();
  if (t == 0) { flags[0] = (cnt >= 192) ? 1 : 0; flags[1] = (oddnz == 0) ? 1 : 0; }
}

// ---- edge_index -> int32 src/dst + degree histogram ----
__global__ __launch_bounds__(256) void convert_idx(
    const unsigned int* __restrict__ eidx, int* __restrict__ srcN, int* __restrict__ dstN,
    int* __restrict__ deg, int E, const int* __restrict__ flags)
{
  int ee = blockIdx.x * 256 + threadIdx.x;
  if (ee >= E) return;
  int s, d;
  if (flags[1]) {
    s = (int)eidx[2 * (size_t)ee];
    d = (int)eidx[2 * ((size_t)E + ee)];
  } else {
    s = (int)eidx[ee];
    d = (int)eidx[(size_t)E + ee];
  }
  srcN[ee] = s;
  dstN[ee] = d;
  atomicAdd(&deg[d], 1);
}

static inline __device__ float ldadapt(const void* p, size_t i, int isbf) {
  return isbf ? b2f(((const unsigned short*)p)[i]) : ((const float*)p)[i];
}

// ---- features -> bf16 (or pass-through copy) ----
__global__ __launch_bounds__(256) void convb_kernel(
    const void* __restrict__ in, unsigned short* __restrict__ outb, size_t n4,
    const int* __restrict__ flags)
{
  const int fb = flags[0];
  size_t i = (size_t)blockIdx.x * 256 + threadIdx.x;
  size_t stride = (size_t)gridDim.x * 256;
  if (fb) {
    const ushort4* ip = (const ushort4*)in;
    ushort4* op = (ushort4*)outb;
    for (; i < n4; i += stride) op[i] = ip[i];
  } else {
    const float4* ip = (const float4*)in;
    ushort4* op = (ushort4*)outb;
    for (; i < n4; i += stride) {
      float4 v = ip[i];
      ushort4 o; o.x = f2b(v.x); o.y = f2b(v.y); o.z = f2b(v.z); o.w = f2b(v.w);
      op[i] = o;
    }
  }
}

// ---- weight prep: W1b [512][256] bf16, W1tb [256][512] bf16, W2f f32, att f32 ----
__global__ __launch_bounds__(256) void prep_weights(
    const void* __restrict__ W1, const void* __restrict__ W2,
    const void* __restrict__ aS, const void* __restrict__ aD,
    unsigned short* __restrict__ W1b, unsigned short* __restrict__ W1tb,
    float* __restrict__ W2f,
    float* __restrict__ atS, float* __restrict__ atD,
    const int* __restrict__ flags)
{
  const int fb = flags[0];
  int i = blockIdx.x * 256 + threadIdx.x;
  if (i < INDIM * HIDD) {               // W1: [512][256]
    int r = i >> 8, c = i & 255;
    float w0 = ldadapt(W1, i, fb);
    unsigned short wb = f2b(w0);
    W1b[i] = wb;                        // Bt for h4: [512 rows][256 k]
    W1tb[c * INDIM + r] = wb;           // Bt for xp1: [256 rows][512 k]
  }
  if (i < HIDD * OUTD) W2f[i] = ldadapt(W2, i, fb);
  if (i < HIDD) { atS[i] = ldadapt(aS, i, fb); atD[i] = ldadapt(aD, i, fb); }
}

// ---- M2 = W2 @ W2^T : [256][256] bf16 (symmetric) ----
__global__ __launch_bounds__(256) void m2_kernel(const float* __restrict__ W2f,
                                                 unsigned short* __restrict__ M2b)
{
  int i = blockIdx.x, j = threadIdx.x;
  float s = 0.f;
#pragma unroll
  for (int o = 0; o < OUTD; ++o) s += W2f[i * OUTD + o] * W2f[j * OUTD + o];
  M2b[i * HIDD + j] = f2b(s);
}

// =====================================================================
// m97-structure MFMA NT GEMM: C[M][Nn] = A[M][K](bf16) @ Bt[Nn][K]^T(bf16)
// 128x128 tile, BK=64, 256 thr = 4 waves (2x2 of 64x64), linear LDS,
// global_load_lds 16B staging, 2 barriers per K-step.
// A must have ceil(M/128)*128 valid (readable) rows. Nn % 128 == 0, K % 64 == 0.
// OUTMODE: 0 = store bf16 to Cb; 1 = adaptive store to Out+outOff (flags[0])
// =====================================================================
template<int OUTMODE>
__global__ __launch_bounds__(256) void gemm_nt2(
    const unsigned short* __restrict__ A, const unsigned short* __restrict__ Bt,
    unsigned short* __restrict__ Cb, void* __restrict__ Out, size_t outOff,
    const int* __restrict__ flags, int M, int Nn, int K)
{
  __shared__ unsigned short Als[128 * 64];
  __shared__ unsigned short Bls[128 * 64];
  const int tid = threadIdx.x, lane = tid & 63, wid = tid >> 6;
  const int wr = wid >> 1, wc = wid & 1;
  const int rowBase = blockIdx.y * 128, colBase = blockIdx.x * 128;
  const int fb = flags[0];

  // staging geometry: instr i of wave wid covers LDS bytes [(wid*4+i)*1024, +1024)
  // lane writes 16B at +lane*16  ->  row = wid*32+i*8+(lane>>3), granule = lane&7
  const int srow = (lane >> 3), sg = lane & 7;

  f32x4 acc[4][4] = {};

  for (int kt = 0; kt < K; kt += 64) {
#pragma unroll
    for (int i = 0; i < 4; ++i) {
      int row = wid * 32 + i * 8 + srow;
      gld16(A + (size_t)(rowBase + row) * K + kt + sg * 8, Als + (wid * 4 + i) * 512);
      gld16(Bt + (size_t)(colBase + row) * K + kt + sg * 8, Bls + (wid * 4 + i) * 512);
    }
    __syncthreads();   // drains vmcnt: staged tiles visible in LDS

    bf16x8 af[4], bfr[4];
#pragma unroll
    for (int ks = 0; ks < 2; ++ks) {
      int g = ks * 4 + (lane >> 4);
#pragma unroll
      for (int mi = 0; mi < 4; ++mi) {
        int row = wr * 64 + mi * 16 + (lane & 15);
        af[mi] = *(const bf16x8*)(Als + row * 64 + g * 8);
      }
#pragma unroll
      for (int ni = 0; ni < 4; ++ni) {
        int row = wc * 64 + ni * 16 + (lane & 15);
        bfr[ni] = *(const bf16x8*)(Bls + row * 64 + g * 8);
      }
#pragma unroll
      for (int mi = 0; mi < 4; ++mi)
#pragma unroll
        for (int ni = 0; ni < 4; ++ni)
          acc[mi][ni] = __builtin_amdgcn_mfma_f32_16x16x32_bf16(af[mi], bfr[ni], acc[mi][ni], 0, 0, 0);
    }
    __syncthreads();   // protect LDS before next stage
  }

  // C/D: col = lane&15, row = (lane>>4)*4 + reg  [verified in r3 pass]
#pragma unroll
  for (int mi = 0; mi < 4; ++mi) {
    int r0 = rowBase + wr * 64 + mi * 16 + (lane >> 4) * 4;
#pragma unroll
    for (int ni = 0; ni < 4; ++ni) {
      int c = colBase + wc * 64 + ni * 16 + (lane & 15);
#pragma unroll
      for (int v = 0; v < 4; ++v) {
        int r = r0 + v;
        if (r < M) {
          size_t idx = (size_t)r * Nn + c;
          if (OUTMODE == 0) Cb[idx] = f2b(acc[mi][ni][v]);
          else {
            if (fb) ((unsigned short*)Out)[outOff + idx] = f2b(acc[mi][ni][v]);
            else    ((float*)Out)[outOff + idx] = acc[mi][ni][v];
          }
        }
      }
    }
  }
}

// ---- a_src / a_dst: one wave per node, dot(xp1_row, att); P is bf16 ----
__global__ __launch_bounds__(256) void rowdots(
    const unsigned short* __restrict__ P, const float* __restrict__ atS,
    const float* __restrict__ atD,
    float* __restrict__ asrc, float* __restrict__ adst, int N)
{
  int wave = threadIdx.x >> 6, lane = threadIdx.x & 63;
  int node = blockIdx.x * 4 + wave;
  if (node >= N) return;
  ushort4 u = *(const ushort4*)(P + (size_t)node * HIDD + lane * 4);
  float4 v = make_float4(b2f(u.x), b2f(u.y), b2f(u.z), b2f(u.w));
  float4 s = *(const float4*)(atS + lane * 4);
  float4 d = *(const float4*)(atD + lane * 4);
  float s1 = v.x * s.x + v.y * s.y + v.z * s.z + v.w * s.w;
  float s2 = v.x * d.x + v.y * d.y + v.z * d.z + v.w * d.w;
#pragma unroll
  for (int off = 32; off; off >>= 1) {
    s1 += __shfl_down(s1, off);
    s2 += __shfl_down(s2, off);
  }
  if (lane == 0) { asrc[node] = s1; adst[node] = s2; }
}

// ---- CSR scan + fill ----
__global__ __launch_bounds__(1024) void scan_kernel(const int* __restrict__ deg, int* __restrict__ offs, int N) {
  __shared__ int part[1024];
  int t = threadIdx.x;
  int chunk = (N + 1023) >> 10;
  int beg = t * chunk;
  int end = beg + chunk; if (end > N) end = N;
  int s = 0;
  for (int i = beg; i < end; ++i) s += deg[i];
  part[t] = s;
  __syncthreads();
  for (int off = 1; off < 1024; off <<= 1) {
    int v = (t >= off) ? part[t - off] : 0;
    __syncthreads();
    part[t] += v;
    __syncthreads();
  }
  int run = (t == 0) ? 0 : part[t - 1];
  for (int i = beg; i < end; ++i) { offs[i] = run; run += deg[i]; }
  if (t == 1023) offs[N] = part[1023];
}

__global__ __launch_bounds__(256) void fill_kernel(const int* __restrict__ dst, int* __restrict__ cur,
                                                   int* __restrict__ perm, int E) {
  int e = blockIdx.x * 256 + threadIdx.x;
  if (e < E) {
    int pos = atomicAdd(&cur[dst[e]], 1);
    perm[pos] = e;
  }
}

// ---- edge coefficient: t = exp(sigmoid(asrc[s]+adst[d])); srec[d] += t ----
// (normalization by srec fused into agg_elu2)
__global__ __launch_bounds__(256) void coef_kernel(
    const int* __restrict__ src, const int* __restrict__ dst,
    const float* __restrict__ asrc, const float* __restrict__ adst,
    float* __restrict__ coef, float* __restrict__ srec, int E)
{
  int e = blockIdx.x * 256 + threadIdx.x;
  if (e >= E) return;
  float x = asrc[src[e]] + adst[dst[e]];
  float al = 1.f / (1.f + __expf(-x));    // sigmoid in (0,1): segment-max unneeded
  float t = __expf(al);
  coef[e] = t;
  atomicAdd(&srec[dst[e]], t);
}

// ---- aggregation: wave per node, 4 channels/lane, fused /denom + ELU ----
__global__ __launch_bounds__(256) void agg_elu2(
    const unsigned short* __restrict__ xp, const float* __restrict__ coef,
    const float* __restrict__ srec,
    const int* __restrict__ srcN, const int* __restrict__ perm,
    const int* __restrict__ offs, unsigned short* __restrict__ hout, int N)
{
  __shared__ int   sS[4][64];
  __shared__ float sW[4][64];
  int wid = threadIdx.x >> 6, lane = threadIdx.x & 63;
  int node = blockIdx.x * 4 + wid;
  if (node >= N) return;
  int s0 = offs[node], s1 = offs[node + 1];
  float a0 = 0.f, a1 = 0.f, a2 = 0.f, a3 = 0.f;
  for (int base = s0; base < s1; base += 64) {
    int cnt = s1 - base; if (cnt > 64) cnt = 64;
    if (lane < cnt) {
      int e = perm[base + lane];
      sS[wid][lane] = srcN[e];
      sW[wid][lane] = coef[e];
    }
    asm volatile("s_waitcnt lgkmcnt(0)" ::: "memory");   // wave-local LDS RAW fence
    int   sp = sS[wid][0];
    float wp = sW[wid][0];
    ushort4 u = *(const ushort4*)(xp + (size_t)sp * HIDD + lane * 4);
    for (int j = 1; j < cnt; ++j) {
      int   sj = sS[wid][j];
      float wj = sW[wid][j];
      ushort4 un = *(const ushort4*)(xp + (size_t)sj * HIDD + lane * 4);  // prefetch
      a0 += wp * b2f(u.x); a1 += wp * b2f(u.y); a2 += wp * b2f(u.z); a3 += wp * b2f(u.w);
      u = un; wp = wj;
    }
    a0 += wp * b2f(u.x); a1 += wp * b2f(u.y); a2 += wp * b2f(u.z); a3 += wp * b2f(u.w);
  }
  float inv = 1.f / (srec[node] + 1e-16f);
  float r0 = a0 * inv, r1 = a1 * inv, r2 = a2 * inv, r3 = a3 * inv;
  r0 = r0 > 0.f ? r0 : expm1f(r0);
  r1 = r1 > 0.f ? r1 : expm1f(r1);
  r2 = r2 > 0.f ? r2 : expm1f(r2);
  r3 = r3 > 0.f ? r3 : expm1f(r3);
  ushort4 o; o.x = f2b(r0); o.y = f2b(r1); o.z = f2b(r2); o.w = f2b(r3);
  *(ushort4*)(hout + (size_t)node * HIDD + lane * 4) = o;
}

// ---- h2 = h1 @ W2 ([N,256]x[256,32]) -> adaptive out ----
__global__ __launch_bounds__(256) void gemm_h2(
    const unsigned short* __restrict__ H1, const float* __restrict__ W2f,
    void* __restrict__ Out, const int* __restrict__ flags, int M)
{
  const int fb = flags[0];
  __shared__ float Bs[HIDD][33];
  __shared__ float As[8][HIDD];
  int tid = threadIdx.x;
  int tx = tid & 31, ty = tid >> 5;
  int row0 = blockIdx.x * 8;
#pragma unroll
  for (int j = 0; j < 32; ++j) {
    int idx = tid + 256 * j;
    Bs[idx >> 5][idx & 31] = W2f[idx];
  }
#pragma unroll
  for (int j = 0; j < 8; ++j) {
    int idx = tid + 256 * j;
    int r = idx >> 8, k = idx & 255;
    As[r][k] = (row0 + r < M) ? b2f(H1[(size_t)(row0 + r) * HIDD + k]) : 0.f;
  }
  __syncthreads();
  float acc = 0.f;
#pragma unroll 8
  for (int k = 0; k < HIDD; ++k) acc += As[ty][k] * Bs[k][tx];
  int row = row0 + ty;
  if (row < M) {
    size_t idx = (size_t)row * OUTD + tx;
    if (fb) ((unsigned short*)Out)[idx] = f2b(acc);
    else    ((float*)Out)[idx] = acc;
  }
}

extern "C" void kernel_launch(void* const* d_in, const int* in_sizes, int n_in,
                              void* d_out, int out_size, void* d_ws, size_t ws_size,
                              hipStream_t stream)
{
  const void*         feat = d_in[0];
  const unsigned int* eidx = (const unsigned int*)d_in[1];
  const void*         W1   = d_in[2];
  const void*         W2   = d_in[3];
  const void*         aS   = d_in[4];
  const void*         aD   = d_in[5];

  const int N = in_sizes[0] / INDIM;
  const int E = in_sizes[1] / 2;
  const int M_pad = ((N + 127) / 128) * 128;

  char* w = (char*)d_ws;
  auto alloc = [&](size_t bytes) -> char* {
    char* p = w; w += (bytes + 255) & ~(size_t)255; return p;
  };
  unsigned short* featb = (unsigned short*)alloc((size_t)M_pad * INDIM * 2); // bf16 features
  unsigned short* H     = featb;   // ALIAS: h1/h3 [M_pad][256] — featb dead after xp1
  unsigned short* P     = (unsigned short*)alloc((size_t)M_pad * HIDD * 2);  // xp1 / xp3
  float* asrc = (float*)alloc((size_t)N * 4);
  float* adst = (float*)alloc((size_t)N * 4);
  float* srec = (float*)alloc((size_t)N * 4);
  float* coef = (float*)alloc((size_t)E * 4);
  int*   deg  = (int*)alloc((size_t)N * 4);
  int*   offs = (int*)alloc((size_t)(N + 1) * 4);
  int*   cur  = (int*)alloc((size_t)N * 4);
  int*   perm = (int*)alloc((size_t)E * 4);
  int*   srcN = (int*)alloc((size_t)E * 4);
  int*   dstN = (int*)alloc((size_t)E * 4);
  unsigned short* W1b  = (unsigned short*)alloc((size_t)INDIM * HIDD * 2); // [512][256]
  unsigned short* W1tb = (unsigned short*)alloc((size_t)INDIM * HIDD * 2); // [256][512]
  unsigned short* M2b  = (unsigned short*)alloc((size_t)HIDD * HIDD * 2);  // [256][256]
  float* W2f  = (float*)alloc((size_t)HIDD * OUTD * 4);
  float* atS  = (float*)alloc((size_t)HIDD * 4);
  float* atD  = (float*)alloc((size_t)HIDD * 4);
  int*   flags = (int*)alloc(64);

  hipMemsetAsync(deg, 0, (size_t)N * 4, stream);
  hipMemsetAsync(srec, 0, (size_t)N * 4, stream);

  probe_kernel<<<1, 256, 0, stream>>>((const unsigned int*)feat, eidx, flags);

  const int eb = (E + 255) / 256;
  convert_idx<<<eb, 256, 0, stream>>>(eidx, srcN, dstN, deg, E, flags);
  prep_weights<<<512, 256, 0, stream>>>(W1, W2, aS, aD, W1b, W1tb, W2f, atS, atD, flags);
  m2_kernel<<<HIDD, HIDD, 0, stream>>>(W2f, M2b);

  // features -> bf16 (pad rows left as-is; GEMM reads them but stores are guarded)
  convb_kernel<<<2048, 256, 0, stream>>>(feat, featb, (size_t)N * INDIM / 4, flags);

  const int mb = (N + 127) / 128;

  // xp1 = featb @ W1 : Bt = W1tb [256][512]
  gemm_nt2<0><<<dim3(HIDD / 128, mb), 256, 0, stream>>>(
      featb, W1tb, P, nullptr, 0, flags, N, HIDD, INDIM);

  rowdots<<<(N + 3) / 4, 256, 0, stream>>>(P, atS, atD, asrc, adst, N);

  scan_kernel<<<1, 1024, 0, stream>>>(deg, offs, N);
  hipMemcpyAsync(cur, offs, (size_t)N * 4, hipMemcpyDeviceToDevice, stream);
  fill_kernel<<<eb, 256, 0, stream>>>(dstN, cur, perm, E);
  coef_kernel<<<eb, 256, 0, stream>>>(srcN, dstN, asrc, adst, coef, srec, E);

  // GAT layer 1: h1 = elu(agg(xp1)/denom)   (H aliases featb — featb dead now)
  agg_elu2<<<(N + 3) / 4, 256, 0, stream>>>(P, coef, srec, srcN, perm, offs, H, N);

  // h2 = h1 @ W2 -> output 0
  gemm_h2<<<(N + 7) / 8, 256, 0, stream>>>(H, W2f, d_out, flags, N);

  // xp3 = h1 @ (W2 W2^T) : Bt = M2b [256][256]
  gemm_nt2<0><<<dim3(HIDD / 128, mb), 256, 0, stream>>>(
      H, M2b, P, nullptr, 0, flags, N, HIDD, HIDD);

  // GAT layer 2 (identical coefficients): h3 = elu(agg(xp3)/denom)
  agg_elu2<<<(N + 3) / 4, 256, 0, stream>>>(P, coef, srec, srcN, perm, offs, H, N);

  // h4 = h3 @ W1^T : Bt = W1b [512][256] -> output 1 (adaptive)
  gemm_nt2<1><<<dim3(INDIM / 128, mb), 256, 0, stream>>>(
      H, W1b, nullptr, d_out, (size_t)N * OUTD, flags, N, INDIM, HIDD);
}

// Round 5
// 1000.035 us; speedup vs baseline: 1.7893x; 1.1841x over previous
//
#include <hip/hip_runtime.h>
#include <cstdint>
#include <cstddef>

#define INDIM 512
#define HIDD  256
#define OUTD  32

typedef __attribute__((ext_vector_type(4))) float f32x4;
typedef __attribute__((ext_vector_type(8))) short bf16x8;

// ---- bf16 <-> f32 helpers ----
static inline __device__ float b2f(unsigned short u) {
  union { float f; unsigned int i; } v; v.i = ((unsigned int)u) << 16; return v.f;
}
static inline __device__ unsigned short f2b(float f) {
  union { float f; unsigned int i; } v; v.f = f;
  unsigned int x = v.i;
  x += 0x7fffu + ((x >> 16) & 1u);   // round-to-nearest-even
  return (unsigned short)(x >> 16);
}

// async global->LDS, 16B per lane. LDS dest = wave-uniform base + lane*16.
static __device__ __forceinline__ void gld16(const unsigned short* g, unsigned short* l) {
  __builtin_amdgcn_global_load_lds(
      (const __attribute__((address_space(1))) void*)g,
      (__attribute__((address_space(3))) void*)l, 16, 0, 0);
}

// ---- runtime dtype probe ----
// flags[0] = 1 if float tensors are bf16 on device, 0 if f32
// flags[1] = 1 if edge_index is int64 on device, 0 if int32
__global__ __launch_bounds__(256) void probe_kernel(
    const unsigned int* __restrict__ feat, const unsigned int* __restrict__ eidx,
    int* __restrict__ flags)
{
  int t = threadIdx.x;
  __shared__ int cnt, oddnz;
  if (t == 0) { cnt = 0; oddnz = 0; }
  __syncthreads();
  unsigned int w = feat[t];
  unsigned short lo = (unsigned short)(w & 0xFFFFu);
  int e = (lo >> 7) & 0xFF;
  int plausible = ((lo & 0x7FFF) == 0) || (e >= 0x60 && e <= 0x9F);
  atomicAdd(&cnt, plausible);
  if (t & 1) { if (eidx[t] != 0u) atomicAdd(&oddnz, 1); }
  __syncthreads();
  if (t == 0) { flags[0] = (cnt >= 192) ? 1 : 0; flags[1] = (oddnz == 0) ? 1 : 0; }
}

// ---- edge_index -> int32 src/dst + degree histogram ----
__global__ __launch_bounds__(256) void convert_idx(
    const unsigned int* __restrict__ eidx, int* __restrict__ srcN, int* __restrict__ dstN,
    int* __restrict__ deg, int E, const int* __restrict__ flags)
{
  int ee = blockIdx.x * 256 + threadIdx.x;
  if (ee >= E) return;
  int s, d;
  if (flags[1]) {
    s = (int)eidx[2 * (size_t)ee];
    d = (int)eidx[2 * ((size_t)E + ee)];
  } else {
    s = (int)eidx[ee];
    d = (int)eidx[(size_t)E + ee];
  }
  srcN[ee] = s;
  dstN[ee] = d;
  atomicAdd(&deg[d], 1);
}

static inline __device__ float ldadapt(const void* p, size_t i, int isbf) {
  return isbf ? b2f(((const unsigned short*)p)[i]) : ((const float*)p)[i];
}

// ---- features -> bf16 (or pass-through copy) ----
__global__ __launch_bounds__(256) void convb_kernel(
    const void* __restrict__ in, unsigned short* __restrict__ outb, size_t n4,
    const int* __restrict__ flags)
{
  const int fb = flags[0];
  size_t i = (size_t)blockIdx.x * 256 + threadIdx.x;
  size_t stride = (size_t)gridDim.x * 256;
  if (fb) {
    const ushort4* ip = (const ushort4*)in;
    ushort4* op = (ushort4*)outb;
    for (; i < n4; i += stride) op[i] = ip[i];
  } else {
    const float4* ip = (const float4*)in;
    ushort4* op = (ushort4*)outb;
    for (; i < n4; i += stride) {
      float4 v = ip[i];
      ushort4 o; o.x = f2b(v.x); o.y = f2b(v.y); o.z = f2b(v.z); o.w = f2b(v.w);
      op[i] = o;
    }
  }
}

// ---- weight prep: W1b [512][256] bf16, W1tb [256][512] bf16, W2f f32, att f32 ----
__global__ __launch_bounds__(256) void prep_weights(
    const void* __restrict__ W1, const void* __restrict__ W2,
    const void* __restrict__ aS, const void* __restrict__ aD,
    unsigned short* __restrict__ W1b, unsigned short* __restrict__ W1tb,
    float* __restrict__ W2f,
    float* __restrict__ atS, float* __restrict__ atD,
    const int* __restrict__ flags)
{
  const int fb = flags[0];
  int i = blockIdx.x * 256 + threadIdx.x;
  if (i < INDIM * HIDD) {               // W1: [512][256]
    int r = i >> 8, c = i & 255;
    float w0 = ldadapt(W1, i, fb);
    unsigned short wb = f2b(w0);
    W1b[i] = wb;                        // Bt for h4: [512 rows][256 k]
    W1tb[c * INDIM + r] = wb;           // Bt for xp1: [256 rows][512 k]
  }
  if (i < HIDD * OUTD) W2f[i] = ldadapt(W2, i, fb);
  if (i < HIDD) { atS[i] = ldadapt(aS, i, fb); atD[i] = ldadapt(aD, i, fb); }
}

// ---- M2 = W2 @ W2^T : [256][256] bf16 (symmetric) ----
__global__ __launch_bounds__(256) void m2_kernel(const float* __restrict__ W2f,
                                                 unsigned short* __restrict__ M2b)
{
  int i = blockIdx.x, j = threadIdx.x;
  float s = 0.f;
#pragma unroll
  for (int o = 0; o < OUTD; ++o) s += W2f[i * OUTD + o] * W2f[j * OUTD + o];
  M2b[i * HIDD + j] = f2b(s);
}

// =====================================================================
// m97-structure MFMA NT GEMM (see r4 notes): C[M][Nn] = A @ Bt^T, bf16 in.
// =====================================================================
template<int OUTMODE>
__global__ __launch_bounds__(256) void gemm_nt2(
    const unsigned short* __restrict__ A, const unsigned short* __restrict__ Bt,
    unsigned short* __restrict__ Cb, void* __restrict__ Out, size_t outOff,
    const int* __restrict__ flags, int M, int Nn, int K)
{
  __shared__ unsigned short Als[128 * 64];
  __shared__ unsigned short Bls[128 * 64];
  const int tid = threadIdx.x, lane = tid & 63, wid = tid >> 6;
  const int wr = wid >> 1, wc = wid & 1;
  const int rowBase = blockIdx.y * 128, colBase = blockIdx.x * 128;
  const int fb = flags[0];

  const int srow = (lane >> 3), sg = lane & 7;

  f32x4 acc[4][4] = {};

  for (int kt = 0; kt < K; kt += 64) {
#pragma unroll
    for (int i = 0; i < 4; ++i) {
      int row = wid * 32 + i * 8 + srow;
      gld16(A + (size_t)(rowBase + row) * K + kt + sg * 8, Als + (wid * 4 + i) * 512);
      gld16(Bt + (size_t)(colBase + row) * K + kt + sg * 8, Bls + (wid * 4 + i) * 512);
    }
    __syncthreads();

    bf16x8 af[4], bfr[4];
#pragma unroll
    for (int ks = 0; ks < 2; ++ks) {
      int g = ks * 4 + (lane >> 4);
#pragma unroll
      for (int mi = 0; mi < 4; ++mi) {
        int row = wr * 64 + mi * 16 + (lane & 15);
        af[mi] = *(const bf16x8*)(Als + row * 64 + g * 8);
      }
#pragma unroll
      for (int ni = 0; ni < 4; ++ni) {
        int row = wc * 64 + ni * 16 + (lane & 15);
        bfr[ni] = *(const bf16x8*)(Bls + row * 64 + g * 8);
      }
#pragma unroll
      for (int mi = 0; mi < 4; ++mi)
#pragma unroll
        for (int ni = 0; ni < 4; ++ni)
          acc[mi][ni] = __builtin_amdgcn_mfma_f32_16x16x32_bf16(af[mi], bfr[ni], acc[mi][ni], 0, 0, 0);
    }
    __syncthreads();
  }

  // C/D: col = lane&15, row = (lane>>4)*4 + reg
#pragma unroll
  for (int mi = 0; mi < 4; ++mi) {
    int r0 = rowBase + wr * 64 + mi * 16 + (lane >> 4) * 4;
#pragma unroll
    for (int ni = 0; ni < 4; ++ni) {
      int c = colBase + wc * 64 + ni * 16 + (lane & 15);
#pragma unroll
      for (int v = 0; v < 4; ++v) {
        int r = r0 + v;
        if (r < M) {
          size_t idx = (size_t)r * Nn + c;
          if (OUTMODE == 0) Cb[idx] = f2b(acc[mi][ni][v]);
          else {
            if (fb) ((unsigned short*)Out)[outOff + idx] = f2b(acc[mi][ni][v]);
            else    ((float*)Out)[outOff + idx] = acc[mi][ni][v];
          }
        }
      }
    }
  }
}

// ---- a_src / a_dst: one wave per node, dot(xp1_row, att); P is bf16 ----
__global__ __launch_bounds__(256) void rowdots(
    const unsigned short* __restrict__ P, const float* __restrict__ atS,
    const float* __restrict__ atD,
    float* __restrict__ asrc, float* __restrict__ adst, int N)
{
  int wave = threadIdx.x >> 6, lane = threadIdx.x & 63;
  int node = blockIdx.x * 4 + wave;
  if (node >= N) return;
  ushort4 u = *(const ushort4*)(P + (size_t)node * HIDD + lane * 4);
  float4 v = make_float4(b2f(u.x), b2f(u.y), b2f(u.z), b2f(u.w));
  float4 s = *(const float4*)(atS + lane * 4);
  float4 d = *(const float4*)(atD + lane * 4);
  float s1 = v.x * s.x + v.y * s.y + v.z * s.z + v.w * s.w;
  float s2 = v.x * d.x + v.y * d.y + v.z * d.z + v.w * d.w;
#pragma unroll
  for (int off = 32; off; off >>= 1) {
    s1 += __shfl_down(s1, off);
    s2 += __shfl_down(s2, off);
  }
  if (lane == 0) { asrc[node] = s1; adst[node] = s2; }
}

// ---- multi-block exclusive scan: P1 block sums, P2 scan sums, P3 scatter ----
// BLKELEM = 1024 elements per block (256 thr x 4)
__global__ __launch_bounds__(256) void scan_p1(const int* __restrict__ deg,
                                               int* __restrict__ bsum, int N)
{
  int b = blockIdx.x, t = threadIdx.x;
  int i0 = b * 1024 + t * 4;
  int s = 0;
#pragma unroll
  for (int j = 0; j < 4; ++j) { int i = i0 + j; if (i < N) s += deg[i]; }
  __shared__ int red[256];
  red[t] = s;
  __syncthreads();
  for (int o = 128; o; o >>= 1) {
    if (t < o) red[t] += red[t + o];
    __syncthreads();
  }
  if (t == 0) bsum[b] = red[0];
}

__global__ __launch_bounds__(256) void scan_p2(int* __restrict__ bsum, int nb)
{
  __shared__ int sh[256];
  int t = threadIdx.x;
  int v = (t < nb) ? bsum[t] : 0;
  sh[t] = v;
  __syncthreads();
  for (int o = 1; o < 256; o <<= 1) {
    int u = (t >= o) ? sh[t - o] : 0;
    __syncthreads();
    sh[t] += u;
    __syncthreads();
  }
  if (t < nb) bsum[t] = sh[t] - v;   // exclusive
}

__global__ __launch_bounds__(256) void scan_p3(const int* __restrict__ deg,
                                               const int* __restrict__ bsum,
                                               int* __restrict__ offs, int* __restrict__ cur,
                                               int N, int nb)
{
  int b = blockIdx.x, t = threadIdx.x;
  int i0 = b * 1024 + t * 4;
  int v[4]; int s = 0;
#pragma unroll
  for (int j = 0; j < 4; ++j) { int i = i0 + j; v[j] = (i < N) ? deg[i] : 0; s += v[j]; }
  __shared__ int sh[256];
  sh[t] = s;
  __syncthreads();
  for (int o = 1; o < 256; o <<= 1) {
    int u = (t >= o) ? sh[t - o] : 0;
    __syncthreads();
    sh[t] += u;
    __syncthreads();
  }
  int run = bsum[b] + sh[t] - s;
#pragma unroll
  for (int j = 0; j < 4; ++j) {
    int i = i0 + j;
    if (i < N) { offs[i] = run; cur[i] = run; }
    run += v[j];
  }
  if (b == nb - 1 && t == 255) offs[N] = run;   // total = E
}

__global__ __launch_bounds__(256) void fill_kernel(const int* __restrict__ dst, int* __restrict__ cur,
                                                   int* __restrict__ perm, int E) {
  int e = blockIdx.x * 256 + threadIdx.x;
  if (e < E) {
    int pos = atomicAdd(&cur[dst[e]], 1);
    perm[pos] = e;
  }
}

// ---- edge coefficient: t = exp(sigmoid(asrc[s]+adst[d])); srec[d] += t ----
__global__ __launch_bounds__(256) void coef_kernel(
    const int* __restrict__ src, const int* __restrict__ dst,
    const float* __restrict__ asrc, const float* __restrict__ adst,
    float* __restrict__ coef, float* __restrict__ srec, int E)
{
  int e = blockIdx.x * 256 + threadIdx.x;
  if (e >= E) return;
  float x = asrc[src[e]] + adst[dst[e]];
  float al = 1.f / (1.f + __expf(-x));    // sigmoid in (0,1): segment-max unneeded
  float t = __expf(al);
  coef[e] = t;
  atomicAdd(&srec[dst[e]], t);
}

// ---- aggregation: wave per node, 4 ch/lane, 4 gathers in flight, fused /denom + ELU ----
__global__ __launch_bounds__(256) void agg_elu2(
    const unsigned short* __restrict__ xp, const float* __restrict__ coef,
    const float* __restrict__ srec,
    const int* __restrict__ srcN, const int* __restrict__ perm,
    const int* __restrict__ offs, unsigned short* __restrict__ hout, int N)
{
  __shared__ int   sS[4][64];
  __shared__ float sW[4][64];
  int wid = threadIdx.x >> 6, lane = threadIdx.x & 63;
  int node = blockIdx.x * 4 + wid;
  if (node >= N) return;
  int s0 = offs[node], s1 = offs[node + 1];
  float a0 = 0.f, a1 = 0.f, a2 = 0.f, a3 = 0.f;
  for (int base = s0; base < s1; base += 64) {
    int cnt = s1 - base; if (cnt > 64) cnt = 64;
    if (lane < cnt) {
      int e = perm[base + lane];
      sS[wid][lane] = srcN[e];
      sW[wid][lane] = coef[e];
    }
    asm volatile("s_waitcnt lgkmcnt(0)" ::: "memory");   // wave-local LDS RAW fence
    int j = 0;
    for (; j + 4 <= cnt; j += 4) {
      int   sv0 = sS[wid][j],     sv1 = sS[wid][j + 1];
      int   sv2 = sS[wid][j + 2], sv3 = sS[wid][j + 3];
      float w0 = sW[wid][j],      w1 = sW[wid][j + 1];
      float w2 = sW[wid][j + 2],  w3 = sW[wid][j + 3];
      ushort4 u0 = *(const ushort4*)(xp + (size_t)sv0 * HIDD + lane * 4);
      ushort4 u1 = *(const ushort4*)(xp + (size_t)sv1 * HIDD + lane * 4);
      ushort4 u2 = *(const ushort4*)(xp + (size_t)sv2 * HIDD + lane * 4);
      ushort4 u3 = *(const ushort4*)(xp + (size_t)sv3 * HIDD + lane * 4);
      a0 += w0 * b2f(u0.x) + w1 * b2f(u1.x) + w2 * b2f(u2.x) + w3 * b2f(u3.x);
      a1 += w0 * b2f(u0.y) + w1 * b2f(u1.y) + w2 * b2f(u2.y) + w3 * b2f(u3.y);
      a2 += w0 * b2f(u0.z) + w1 * b2f(u1.z) + w2 * b2f(u2.z) + w3 * b2f(u3.z);
      a3 += w0 * b2f(u0.w) + w1 * b2f(u1.w) + w2 * b2f(u2.w) + w3 * b2f(u3.w);
    }
    for (; j < cnt; ++j) {
      int   sv = sS[wid][j];
      float wv = sW[wid][j];
      ushort4 u = *(const ushort4*)(xp + (size_t)sv * HIDD + lane * 4);
      a0 += wv * b2f(u.x); a1 += wv * b2f(u.y); a2 += wv * b2f(u.z); a3 += wv * b2f(u.w);
    }
  }
  float inv = 1.f / (srec[node] + 1e-16f);
  float r0 = a0 * inv, r1 = a1 * inv, r2 = a2 * inv, r3 = a3 * inv;
  r0 = r0 > 0.f ? r0 : expm1f(r0);
  r1 = r1 > 0.f ? r1 : expm1f(r1);
  r2 = r2 > 0.f ? r2 : expm1f(r2);
  r3 = r3 > 0.f ? r3 : expm1f(r3);
  ushort4 o; o.x = f2b(r0); o.y = f2b(r1); o.z = f2b(r2); o.w = f2b(r3);
  *(ushort4*)(hout + (size_t)node * HIDD + lane * 4) = o;
}

// ---- h2 = h1 @ W2 ([N,256]x[256,32]) -> adaptive out ----
__global__ __launch_bounds__(256) void gemm_h2(
    const unsigned short* __restrict__ H1, const float* __restrict__ W2f,
    void* __restrict__ Out, const int* __restrict__ flags, int M)
{
  const int fb = flags[0];
  __shared__ float Bs[HIDD][33];
  __shared__ float As[8][HIDD];
  int tid = threadIdx.x;
  int tx = tid & 31, ty = tid >> 5;
  int row0 = blockIdx.x * 8;
#pragma unroll
  for (int j = 0; j < 32; ++j) {
    int idx = tid + 256 * j;
    Bs[idx >> 5][idx & 31] = W2f[idx];
  }
#pragma unroll
  for (int j = 0; j < 8; ++j) {
    int idx = tid + 256 * j;
    int r = idx >> 8, k = idx & 255;
    As[r][k] = (row0 + r < M) ? b2f(H1[(size_t)(row0 + r) * HIDD + k]) : 0.f;
  }
  __syncthreads();
  float acc = 0.f;
#pragma unroll 8
  for (int k = 0; k < HIDD; ++k) acc += As[ty][k] * Bs[k][tx];
  int row = row0 + ty;
  if (row < M) {
    size_t idx = (size_t)row * OUTD + tx;
    if (fb) ((unsigned short*)Out)[idx] = f2b(acc);
    else    ((float*)Out)[idx] = acc;
  }
}

extern "C" void kernel_launch(void* const* d_in, const int* in_sizes, int n_in,
                              void* d_out, int out_size, void* d_ws, size_t ws_size,
                              hipStream_t stream)
{
  const void*         feat = d_in[0];
  const unsigned int* eidx = (const unsigned int*)d_in[1];
  const void*         W1   = d_in[2];
  const void*         W2   = d_in[3];
  const void*         aS   = d_in[4];
  const void*         aD   = d_in[5];

  const int N = in_sizes[0] / INDIM;
  const int E = in_sizes[1] / 2;
  const int M_pad = ((N + 127) / 128) * 128;
  const int nb = (N + 1023) / 1024;

  char* w = (char*)d_ws;
  auto alloc = [&](size_t bytes) -> char* {
    char* p = w; w += (bytes + 255) & ~(size_t)255; return p;
  };
  unsigned short* featb = (unsigned short*)alloc((size_t)M_pad * INDIM * 2); // bf16 features
  unsigned short* H     = featb;   // ALIAS: h1/h3 [M_pad][256] — featb dead after xp1
  unsigned short* P     = (unsigned short*)alloc((size_t)M_pad * HIDD * 2);  // xp1 / xp3
  float* asrc = (float*)alloc((size_t)N * 4);
  float* adst = (float*)alloc((size_t)N * 4);
  float* srec = (float*)alloc((size_t)N * 4);
  float* coef = (float*)alloc((size_t)E * 4);
  int*   deg  = (int*)alloc((size_t)N * 4);
  int*   offs = (int*)alloc((size_t)(N + 1) * 4);
  int*   cur  = (int*)alloc((size_t)N * 4);
  int*   perm = (int*)alloc((size_t)E * 4);
  int*   srcN = (int*)alloc((size_t)E * 4);
  int*   dstN = (int*)alloc((size_t)E * 4);
  int*   bsum = (int*)alloc((size_t)(nb + 1) * 4);
  unsigned short* W1b  = (unsigned short*)alloc((size_t)INDIM * HIDD * 2); // [512][256]
  unsigned short* W1tb = (unsigned short*)alloc((size_t)INDIM * HIDD * 2); // [256][512]
  unsigned short* M2b  = (unsigned short*)alloc((size_t)HIDD * HIDD * 2);  // [256][256]
  float* W2f  = (float*)alloc((size_t)HIDD * OUTD * 4);
  float* atS  = (float*)alloc((size_t)HIDD * 4);
  float* atD  = (float*)alloc((size_t)HIDD * 4);
  int*   flags = (int*)alloc(64);

  hipMemsetAsync(deg, 0, (size_t)N * 4, stream);
  hipMemsetAsync(srec, 0, (size_t)N * 4, stream);

  probe_kernel<<<1, 256, 0, stream>>>((const unsigned int*)feat, eidx, flags);

  const int eb = (E + 255) / 256;
  convert_idx<<<eb, 256, 0, stream>>>(eidx, srcN, dstN, deg, E, flags);
  prep_weights<<<512, 256, 0, stream>>>(W1, W2, aS, aD, W1b, W1tb, W2f, atS, atD, flags);
  m2_kernel<<<HIDD, HIDD, 0, stream>>>(W2f, M2b);

  // features -> bf16
  convb_kernel<<<2048, 256, 0, stream>>>(feat, featb, (size_t)N * INDIM / 4, flags);

  const int mb = (N + 127) / 128;

  // xp1 = featb @ W1 : Bt = W1tb [256][512]
  gemm_nt2<0><<<dim3(HIDD / 128, mb), 256, 0, stream>>>(
      featb, W1tb, P, nullptr, 0, flags, N, HIDD, INDIM);

  rowdots<<<(N + 3) / 4, 256, 0, stream>>>(P, atS, atD, asrc, adst, N);

  // CSR offsets: multi-block scan (P3 also initializes cur = offs)
  scan_p1<<<nb, 256, 0, stream>>>(deg, bsum, N);
  scan_p2<<<1, 256, 0, stream>>>(bsum, nb);
  scan_p3<<<nb, 256, 0, stream>>>(deg, bsum, offs, cur, N, nb);
  fill_kernel<<<eb, 256, 0, stream>>>(dstN, cur, perm, E);
  coef_kernel<<<eb, 256, 0, stream>>>(srcN, dstN, asrc, adst, coef, srec, E);

  // GAT layer 1: h1 = elu(agg(xp1)/denom)   (H aliases featb — featb dead now)
  agg_elu2<<<(N + 3) / 4, 256, 0, stream>>>(P, coef, srec, srcN, perm, offs, H, N);

  // h2 = h1 @ W2 -> output 0
  gemm_h2<<<(N + 7) / 8, 256, 0, stream>>>(H, W2f, d_out, flags, N);

  // xp3 = h1 @ (W2 W2^T) : Bt = M2b [256][256]
  gemm_nt2<0><<<dim3(HIDD / 128, mb), 256, 0, stream>>>(
      H, M2b, P, nullptr, 0, flags, N, HIDD, HIDD);

  // GAT layer 2 (identical coefficients): h3 = elu(agg(xp3)/denom)
  agg_elu2<<<(N + 3) / 4, 256, 0, stream>>>(P, coef, srec, srcN, perm, offs, H, N);

  // h4 = h3 @ W1^T : Bt = W1b [512][256] -> output 1 (adaptive)
  gemm_nt2<1><<<dim3(INDIM / 128, mb), 256, 0, stream>>>(
      H, W1b, nullptr, d_out, (size_t)N * OUTD, flags, N, INDIM, HIDD);
}